// Round 1
// baseline (101.877 us; speedup 1.0000x reference)
//
#include <hip/hip_runtime.h>

// NeuralCA: out = clip(x + sum_k sigmoid(10*(conv3x3_k(x) - r_k)) * (p_k - x), 0, 1)
// B=16, H=W=512, NK=16. fp32 throughout (no fp32 MFMA on CDNA4; bf16 MFMA too
// precision-risky through GAIN=10 sigmoid). Compute-bound on VALU (~604M conv FMA
// + 67M exp/rcp pairs); HBM floor is only ~5us (32MB), est compute ~15us.

#define NK 16
#define BATCH 16
#define H 512
#define W 512
#define GAIN 10.0f

__global__ __launch_bounds__(256) void nca_kernel(
    const float* __restrict__ x,
    const float* __restrict__ kernels,
    const float* __restrict__ reactants,
    const float* __restrict__ products,
    float* __restrict__ out)
{
    // One thread per 1x4 pixel strip. Total strips = 16*512*128 = 2^20, exact grid fit.
    const int idx = blockIdx.x * blockDim.x + threadIdx.x;
    const int w4 = (idx & 127) << 2;      // strip start col (W/4 = 128 strips/row)
    const int h  = (idx >> 7) & 511;
    const int b  = idx >> 16;

    const float* xb = x + (size_t)b * H * W;

    // 3 rows x 6 cols register window (halo of 1 on each side in w)
    float v[3][6];
#pragma unroll
    for (int r = 0; r < 3; ++r) {
        const int row = h + r - 1;
        if (row >= 0 && row < H) {
            const float* xr = xb + row * W;
            const float4 c = *(const float4*)(xr + w4);
            v[r][1] = c.x; v[r][2] = c.y; v[r][3] = c.z; v[r][4] = c.w;
            v[r][0] = (w4 > 0)     ? xr[w4 - 1] : 0.0f;   // zero pad left
            v[r][5] = (w4 + 4 < W) ? xr[w4 + 4] : 0.0f;   // zero pad right
        } else {
#pragma unroll
            for (int c = 0; c < 6; ++c) v[r][c] = 0.0f;   // zero pad top/bottom
        }
    }

    // delta = sum_k sig_k*(p_k - x) = (sum_k sig_k*p_k) - x*(sum_k sig_k)
    float s0[4] = {0.f, 0.f, 0.f, 0.f};   // sum of sigmoids
    float s1[4] = {0.f, 0.f, 0.f, 0.f};   // sum of sigmoid * product

    for (int k = 0; k < NK; ++k) {
        // Uniform indices -> scalar loads (SGPR broadcast), no per-lane VALU cost
        float wk[9];
#pragma unroll
        for (int i = 0; i < 9; ++i) wk[i] = kernels[k * 9 + i];
        const float c0 = -GAIN * reactants[k];
        const float pk = products[k];

#pragma unroll
        for (int p = 0; p < 4; ++p) {
            float n = 0.0f;
#pragma unroll
            for (int r = 0; r < 3; ++r)
#pragma unroll
                for (int c = 0; c < 3; ++c)
                    n = fmaf(v[r][p + c], wk[r * 3 + c], n);
            const float z = fmaf(GAIN, n, c0);            // 10*(N - r_k)
            // sigmoid(z) = 1/(1 + exp(-z)); fast exp + v_rcp_f32 (plenty for 2e-2 abs tol)
            const float e = __expf(-z);
            const float sig = __builtin_amdgcn_rcpf(1.0f + e);
            s0[p] += sig;
            s1[p] = fmaf(sig, pk, s1[p]);
        }
    }

    float4 o;
    float* op = &o.x;
#pragma unroll
    for (int p = 0; p < 4; ++p) {
        const float xv = v[1][p + 1];
        float res = xv + s1[p] - xv * s0[p];
        res = fminf(fmaxf(res, 0.0f), 1.0f);
        op[p] = res;
    }
    *(float4*)(out + (size_t)idx * 4) = o;
}

extern "C" void kernel_launch(void* const* d_in, const int* in_sizes, int n_in,
                              void* d_out, int out_size, void* d_ws, size_t ws_size,
                              hipStream_t stream) {
    const float* x         = (const float*)d_in[0];
    const float* kernels   = (const float*)d_in[1];
    const float* reactants = (const float*)d_in[2];
    const float* products  = (const float*)d_in[3];
    float* out = (float*)d_out;

    const int total_strips = BATCH * H * (W / 4);  // 2^20
    nca_kernel<<<total_strips / 256, 256, 0, stream>>>(x, kernels, reactants, products, out);
}

// Round 2
// 100.212 us; speedup vs baseline: 1.0166x; 1.0166x over previous
//
#include <hip/hip_runtime.h>

// NeuralCA: out = clip(x + sum_k sigmoid(10*(conv3x3_k(x) - r_k)) * (p_k - x), 0, 1)
// B=16, H=W=512, NK=16, fp32. Compute-bound on VALU/trans pipe; HBM floor ~8us.
// R2: addrspace(4) scalar table loads + full k-unroll + raw v_exp_f32 sigmoid
//     + 2x4 pixel tile per thread (8 independent sigmoid chains for latency hiding).

#define NK 16
#define BATCH 16
#define H 512
#define W 512
#define G2 14.4269504088896340f   // GAIN(=10) * log2(e)

#if __has_builtin(__builtin_amdgcn_exp2f)
#define EXP2F(x) __builtin_amdgcn_exp2f(x)
#else
#define EXP2F(x) exp2f(x)
#endif

// Constant address space -> guaranteed s_load (SGPR broadcast, no VALU/vmem cost)
typedef const __attribute__((address_space(4))) float cfloat;

__global__ __launch_bounds__(256) void nca_kernel(
    const float* __restrict__ x,
    const float* __restrict__ kernels,
    const float* __restrict__ reactants,
    const float* __restrict__ products,
    float* __restrict__ out)
{
    // One thread per 2x4 pixel tile. Tiles: 16 * 256 * 128 = 2^19 threads.
    const int idx = blockIdx.x * blockDim.x + threadIdx.x;
    const int w4 = (idx & 127) << 2;        // tile start col (128 tiles/row)
    const int h0 = ((idx >> 7) & 255) << 1; // tile start row
    const int b  = idx >> 15;

    const float* xb = x + (size_t)b * (H * W);

    // 4 rows x 6 cols register window (rows h0-1 .. h0+2, halo 1 each side in w)
    float v[4][6];
#pragma unroll
    for (int r = 0; r < 4; ++r) {
        const int row = h0 + r - 1;
        if (row >= 0 && row < H) {
            const float* xr = xb + row * W;
            const float4 c = *(const float4*)(xr + w4);
            v[r][1] = c.x; v[r][2] = c.y; v[r][3] = c.z; v[r][4] = c.w;
            v[r][0] = (w4 > 0)     ? xr[w4 - 1] : 0.0f;   // zero pad left
            v[r][5] = (w4 + 4 < W) ? xr[w4 + 4] : 0.0f;   // zero pad right
        } else {
#pragma unroll
            for (int c = 0; c < 6; ++c) v[r][c] = 0.0f;   // zero pad top/bottom
        }
    }

    cfloat* kc = (cfloat*)kernels;
    cfloat* rc = (cfloat*)reactants;
    cfloat* pc = (cfloat*)products;

    // delta = sum_k sig_k*(p_k - x) = (sum_k sig_k*p_k) - x*(sum_k sig_k)
    float s0[2][4] = {{0.f,0.f,0.f,0.f},{0.f,0.f,0.f,0.f}};  // sum sig
    float s1[2][4] = {{0.f,0.f,0.f,0.f},{0.f,0.f,0.f,0.f}};  // sum sig*p_k

#pragma unroll
    for (int k = 0; k < NK; ++k) {
        float wk[9];
#pragma unroll
        for (int i = 0; i < 9; ++i) wk[i] = kc[k * 9 + i];
        const float c2 = G2 * rc[k];   // t = c2 - G2*N  =>  2^t = exp(-10*(N-r_k))
        const float pk = pc[k];

#pragma unroll
        for (int py = 0; py < 2; ++py) {
#pragma unroll
            for (int p = 0; p < 4; ++p) {
                float n = 0.0f;
#pragma unroll
                for (int r = 0; r < 3; ++r)
#pragma unroll
                    for (int c = 0; c < 3; ++c)
                        n = fmaf(v[py + r][p + c], wk[r * 3 + c], n);
                const float t = fmaf(-G2, n, c2);
                const float e = EXP2F(t);                       // v_exp_f32
                const float sig = __builtin_amdgcn_rcpf(1.0f + e);
                s0[py][p] += sig;
                s1[py][p] = fmaf(sig, pk, s1[py][p]);
            }
        }
    }

#pragma unroll
    for (int py = 0; py < 2; ++py) {
        float4 o;
        float* op = &o.x;
#pragma unroll
        for (int p = 0; p < 4; ++p) {
            const float xv = v[py + 1][p + 1];
            float res = xv + s1[py][p] - xv * s0[py][p];
            op[p] = fminf(fmaxf(res, 0.0f), 1.0f);
        }
        *(float4*)(out + ((size_t)(b * H + h0 + py) * W + w4)) = o;
    }
}

extern "C" void kernel_launch(void* const* d_in, const int* in_sizes, int n_in,
                              void* d_out, int out_size, void* d_ws, size_t ws_size,
                              hipStream_t stream) {
    const float* x         = (const float*)d_in[0];
    const float* kernels   = (const float*)d_in[1];
    const float* reactants = (const float*)d_in[2];
    const float* products  = (const float*)d_in[3];
    float* out = (float*)d_out;

    const int total_tiles = BATCH * (H / 2) * (W / 4);  // 2^19
    nca_kernel<<<total_tiles / 256, 256, 0, stream>>>(x, kernels, reactants, products, out);
}